// Round 4
// baseline (206.834 us; speedup 1.0000x reference)
//
#include <hip/hip_runtime.h>
#include <math.h>

// PPO loss with GAE.  B=4096 rows, T=2048 steps, fp32 inputs.
// Inputs: 0 rewards(B,T) 1 values(B,T+1) 2 ref_probs(UNUSED) 3 old_probs(B,T)
//         4 curr_probs(B,T) 5 masks(B,T)
// Output: 4 floats: total, ppo, 0.5*value_loss, 0.01*entropy_loss
//
// R9: R5/R6/R8 all compiled to the same serialized-load pattern (VGPR 40-48)
// regardless of source structure -- compiler sinks loads to uses to hold ~8
// waves/EU pressure. gae stuck at 42us vs ~15us floor, latency-bound.
// This round FORCES memory-level parallelism with inline asm:
//   - 7x asm volatile global_load_dwordx4 (unsinkable, ordered)
//   - s_waitcnt vmcnt(0) asm that ties all 7 results as "+v" -> every use is
//     data-dependent on the wait; + sched_barrier(0) (rule #18)
//   - 1 row/block, 4096 blocks, launch_bounds(256,4) -> ~16 waves/CU, each
//     wave holds 7KB of loads in one latency shadow (~112KB/CU in flight).
// Tell: gae VGPR >= 72 and dur ~17-24us. If VGPR ~48 again, asm was defeated.

#define GAMMA     0.99f
#define LAM       0.95f
#define CLIP_LO   0.8f
#define CLIP_HI   1.2f
#define EPSF      1e-9f

constexpr int BB = 4096;
constexpr int TT = 2048;
constexpr long long NN = (long long)BB * TT;   // 8388608
constexpr int GAE_BLOCKS = BB;                 // 1 row per block
constexpr int PPO_BLOCKS = 4096;               // 8 elems/thread

// ws layout:
//  [0,32)          stats: float mean, float inv_std_eps, double sum_adv2
//  [64, +32K)      gae partials: 4096 x float2
//  [32832, +32K)   ppo partials: 4096 x float2
//  [65600, +16.8M) adv in bf16 (uint4-aligned; 65600 % 16 == 0)
struct Stats { float mean; float inv; double sum2; };
static constexpr size_t GAE_PART_OFF = 64;
static constexpr size_t PPO_PART_OFF = GAE_PART_OFF + GAE_BLOCKS * sizeof(float2); // 32832
static constexpr size_t ADV_OFF      = PPO_PART_OFF + PPO_BLOCKS * sizeof(float2); // 65600

typedef float f32x4 __attribute__((ext_vector_type(4)));

__device__ __forceinline__ unsigned bf16_rne(float x) {
    unsigned u = __float_as_uint(x);
    u += 0x7FFFu + ((u >> 16) & 1u);
    return u >> 16;
}

// Forced 16B global load: volatile asm cannot be sunk, split, or re-batched.
#define GLOAD(dst, p) \
    asm volatile("global_load_dwordx4 %0, %1, off" : "=v"(dst) : "v"(p))

// ---------------------------------------------------------------- K1: GAE scan
__global__ __launch_bounds__(256, 4) void gae_kernel(
    const float* __restrict__ rewards,
    const float* __restrict__ values,
    const float* __restrict__ masks,
    uint4* __restrict__ advb,          // bf16 x8 per uint4
    float2* __restrict__ partials)
{
    const int tid  = threadIdx.x;
    const int lane = tid & 63;
    const int wave = tid >> 6;
    const int t0   = tid * 8;
    const int r    = blockIdx.x;

    __shared__ float2 wT[4];
    __shared__ float  wr1[4], wr2[4];

    // rewards/masks rows: stride 2048 floats -> every float4 aligned.
    const float* rp = rewards + (size_t)r * TT;
    const float* mp = masks   + (size_t)r * TT;
    // values row: stride 2049 -> aligned 3x float4 window from (vw & ~3);
    // needed words are window[ofs .. ofs+8], ofs = r & 3 (block-uniform).
    const size_t vw = (size_t)r * (TT + 1);
    const int    ofs = (int)(vw & 3);
    const f32x4* v4 = (const f32x4*)(values + (vw & ~(size_t)3));
    // OOB check: worst case r=4095 (ofs=3), tid=255: F2 covers words
    // 8390652+2040+8..11 = 8392700..8392703; values has 4096*2049 = 8392704
    // words, last index 8392703. Exactly in bounds.

    f32x4 R0, R1, M0, M1, F0, F1, F2;
    GLOAD(R0, (const f32x4*)(rp + t0));
    GLOAD(R1, (const f32x4*)(rp + t0 + 4));
    GLOAD(M0, (const f32x4*)(mp + t0));
    GLOAD(M1, (const f32x4*)(mp + t0 + 4));
    GLOAD(F0, v4 + 2 * tid);
    GLOAD(F1, v4 + 2 * tid + 1);
    GLOAD(F2, v4 + 2 * tid + 2);
    // Single drain; all 7 results tied so every consumer depends on this asm.
    asm volatile("s_waitcnt vmcnt(0)"
                 : "+v"(R0), "+v"(R1), "+v"(M0), "+v"(M1),
                   "+v"(F0), "+v"(F1), "+v"(F2));
    __builtin_amdgcn_sched_barrier(0);

    // ---- extract the 9 needed values (wave-uniform branch, static indices)
    float ff[12] = {F0.x, F0.y, F0.z, F0.w, F1.x, F1.y, F1.z, F1.w,
                    F2.x, F2.y, F2.z, F2.w};
    float vv[9];
    if (ofs == 0) {
#pragma unroll
        for (int j = 0; j < 9; ++j) vv[j] = ff[j];
    } else if (ofs == 1) {
#pragma unroll
        for (int j = 0; j < 9; ++j) vv[j] = ff[j + 1];
    } else if (ofs == 2) {
#pragma unroll
        for (int j = 0; j < 9; ++j) vv[j] = ff[j + 2];
    } else {
#pragma unroll
        for (int j = 0; j < 9; ++j) vv[j] = ff[j + 3];
    }

    float rr[8] = {R0.x, R0.y, R0.z, R0.w, R1.x, R1.y, R1.z, R1.w};
    float mm[8] = {M0.x, M0.y, M0.z, M0.w, M1.x, M1.y, M1.z, M1.w};

    // ---- chunk-local reverse affine scan (verified R4/R5 structure)
    float la[8], S[8];
    {
        float d[8], c[8];
#pragma unroll
        for (int j = 0; j < 8; ++j) {
            d[j] = rr[j] + GAMMA * vv[j + 1] * mm[j] - vv[j];
            c[j] = (GAMMA * LAM) * mm[j];
        }
        la[7] = d[7]; S[7] = c[7];
#pragma unroll
        for (int j = 6; j >= 0; --j) {
            la[j] = d[j] + c[j] * la[j + 1];
            S[j]  = c[j] * S[j + 1];
        }
    }

    // ---- wave-level suffix scan of affine fns
    float A = S[0], Bv = la[0];
#pragma unroll
    for (int d2 = 1; d2 < 64; d2 <<= 1) {
        float A2 = __shfl_down(A, d2, 64), B2 = __shfl_down(Bv, d2, 64);
        if (lane + d2 < 64) { Bv = Bv + A * B2; A = A * A2; }
    }
    if (lane == 0) wT[wave] = make_float2(A, Bv);
    __syncthreads();
    float C = 0.f;
    for (int ww = 3; ww > wave; --ww) C = wT[ww].y + wT[ww].x * C;
    float A1 = __shfl_down(A, 1, 64), B1 = __shfl_down(Bv, 1, 64);
    float car = (lane < 63) ? (B1 + A1 * C) : C;

    // ---- final adv, fp32 sums, bf16 pack + store
    float s1 = 0.f, s2 = 0.f;
    unsigned hh[8];
#pragma unroll
    for (int j = 0; j < 8; ++j) {
        float a = la[j] + S[j] * car;
        s1 += a; s2 += a * a;
        hh[j] = bf16_rne(a);
    }
    uint4 pk = {hh[0] | (hh[1] << 16), hh[2] | (hh[3] << 16),
                hh[4] | (hh[5] << 16), hh[6] | (hh[7] << 16)};
    advb[(size_t)r * 256 + tid] = pk;   // 8 bf16 = 16B per thread, coalesced

    // ---- block reduce -> one float2 per block
#pragma unroll
    for (int off = 32; off > 0; off >>= 1) {
        s1 += __shfl_down(s1, off, 64);
        s2 += __shfl_down(s2, off, 64);
    }
    if (lane == 0) { wr1[wave] = s1; wr2[wave] = s2; }
    __syncthreads();
    if (tid == 0) {
        partials[blockIdx.x] = make_float2(wr1[0] + wr1[1] + wr1[2] + wr1[3],
                                           wr2[0] + wr2[1] + wr2[2] + wr2[3]);
    }
}

// ------------------------------------- K2: reduce gae partials -> mean, inv_std
__global__ __launch_bounds__(256) void finalize_stats(
    const float2* __restrict__ gp, Stats* __restrict__ stats)
{
    const int tid = threadIdx.x;
    __shared__ double l1[256], l2[256];
    double s1 = 0.0, s2 = 0.0;
    for (int i = tid; i < GAE_BLOCKS; i += 256) {
        float2 p = gp[i];
        s1 += (double)p.x;
        s2 += (double)p.y;
    }
    l1[tid] = s1; l2[tid] = s2;
    __syncthreads();
    for (int st = 128; st > 0; st >>= 1) {
        if (tid < st) { l1[tid] += l1[tid + st]; l2[tid] += l2[tid + st]; }
        __syncthreads();
    }
    if (tid == 0) {
        double S1 = l1[0], S2 = l2[0];
        double mean = S1 / (double)NN;
        double var  = (S2 - S1 * S1 / (double)NN) / (double)(NN - 1); // ddof=1
        stats->mean = (float)mean;
        stats->inv  = (float)(1.0 / (sqrt(var) + 1e-9));
        stats->sum2 = S2;
    }
}

// ------------------------------------------------- K3: ppo surrogate + entropy
__global__ __launch_bounds__(256, 8) void ppo_kernel(
    const float* __restrict__ adv_bf16,   // raw bf16 pairs, read as uint4
    const float* __restrict__ oldp,
    const float* __restrict__ currp,
    const Stats* __restrict__ stats,
    float2* __restrict__ partials)
{
    const float mean = stats->mean;
    const float inv  = stats->inv;
    const int tid = threadIdx.x;
    const int g   = blockIdx.x * 256 + tid;     // uint4 index: 8 elems/thread

    const uint4*  a4 = (const uint4*)adv_bf16;
    const float4* o4 = (const float4*)oldp;
    const float4* c4 = (const float4*)currp;

    uint4  A  = a4[g];
    float4 O0 = o4[2 * g], O1 = o4[2 * g + 1];
    float4 C0 = c4[2 * g], C1 = c4[2 * g + 1];

    float av[8] = {__uint_as_float(A.x << 16), __uint_as_float(A.x & 0xFFFF0000u),
                   __uint_as_float(A.y << 16), __uint_as_float(A.y & 0xFFFF0000u),
                   __uint_as_float(A.z << 16), __uint_as_float(A.z & 0xFFFF0000u),
                   __uint_as_float(A.w << 16), __uint_as_float(A.w & 0xFFFF0000u)};
    float ov[8] = {O0.x, O0.y, O0.z, O0.w, O1.x, O1.y, O1.z, O1.w};
    float cv[8] = {C0.x, C0.y, C0.z, C0.w, C1.x, C1.y, C1.z, C1.w};

    float sm = 0.f, se = 0.f;
#pragma unroll
    for (int j = 0; j < 8; ++j) {
        float an    = (av[j] - mean) * inv;
        float ratio = cv[j] * __builtin_amdgcn_rcpf(ov[j] + EPSF);
        float rc    = fminf(fmaxf(ratio, CLIP_LO), CLIP_HI);
        sm += fminf(ratio * an, rc * an);
        se += cv[j] * __logf(cv[j] + EPSF);
    }

#pragma unroll
    for (int off = 32; off > 0; off >>= 1) {
        sm += __shfl_down(sm, off, 64);
        se += __shfl_down(se, off, 64);
    }
    __shared__ float w1[4], w2[4];
    const int wave = tid >> 6, lane = tid & 63;
    if (lane == 0) { w1[wave] = sm; w2[wave] = se; }
    __syncthreads();
    if (tid == 0) {
        float2 p = {w1[0] + w1[1] + w1[2] + w1[3],
                    w2[0] + w2[1] + w2[2] + w2[3]};
        partials[blockIdx.x] = p;
    }
}

// --------------------------------- K4: reduce ppo partials -> 4 output scalars
__global__ __launch_bounds__(256) void finalize_out(
    const float2* __restrict__ pp,
    const Stats* __restrict__ stats,
    float* __restrict__ out)
{
    const int tid = threadIdx.x;
    __shared__ double l1[256], l2[256];
    double s1 = 0.0, s2 = 0.0;
    for (int i = tid; i < PPO_BLOCKS; i += 256) {
        float2 p = pp[i];
        s1 += (double)p.x;
        s2 += (double)p.y;
    }
    l1[tid] = s1; l2[tid] = s2;
    __syncthreads();
    for (int st = 128; st > 0; st >>= 1) {
        if (tid < st) { l1[tid] += l1[tid + st]; l2[tid] += l2[tid + st]; }
        __syncthreads();
    }
    if (tid == 0) {
        double invN = 1.0 / (double)NN;
        double vl   = 0.5  * (stats->sum2 * invN);   // 0.5 * mean(raw_adv^2)
        double ppo  = -(l1[0] * invN);
        double ent  = -0.01 * (l2[0] * invN);
        out[0] = (float)(ppo + vl + ent);
        out[1] = (float)ppo;
        out[2] = (float)vl;
        out[3] = (float)ent;
    }
}

extern "C" void kernel_launch(void* const* d_in, const int* in_sizes, int n_in,
                              void* d_out, int out_size, void* d_ws, size_t ws_size,
                              hipStream_t stream) {
    const float* rewards = (const float*)d_in[0];
    const float* values  = (const float*)d_in[1];
    // d_in[2] = ref_probs: unused by the reference
    const float* oldp    = (const float*)d_in[3];
    const float* currp   = (const float*)d_in[4];
    const float* masks   = (const float*)d_in[5];

    Stats*  stats = (Stats*)d_ws;
    float2* gaep  = (float2*)((char*)d_ws + GAE_PART_OFF);
    float2* ppop  = (float2*)((char*)d_ws + PPO_PART_OFF);
    uint4*  advb  = (uint4*)((char*)d_ws + ADV_OFF);
    float*  out   = (float*)d_out;

    gae_kernel<<<GAE_BLOCKS, 256, 0, stream>>>(rewards, values, masks, advb, gaep);
    finalize_stats<<<1, 256, 0, stream>>>(gaep, stats);
    ppo_kernel<<<PPO_BLOCKS, 256, 0, stream>>>((const float*)advb, oldp, currp, stats, ppop);
    finalize_out<<<1, 256, 0, stream>>>(ppop, stats, out);
}